// Round 1
// baseline (287.241 us; speedup 1.0000x reference)
//
#include <hip/hip_runtime.h>
#include <math.h>

// FedTGPClientLoss: fused CE (log-softmax gather) + prototype-MSE.
// B=16384, C=1000, D=512.
// R4 design: single kernel. One row per wave (4096 blocks x 4 waves), zero
// barriers on the row path. Wave reduction restructured: butterfly-max first,
// ONE rescale exp, then a combined (s,q) sum butterfly (was: 6 merged (m,s)
// steps with 2 exps each). Finalize is fused via the last-block-done pattern:
// a module-scope __device__ counter (zeroed at module load, reset by the
// elected last block each run -> graph-replay safe, no host memset, no
// cooperative launch needed).

#ifndef INFINITY
#define INFINITY __builtin_inff()
#endif

__device__ __forceinline__ float safe_exp(float dm) {
    // exp(min(dm,0)): dm is always <= 0 mathematically; fmin also flushes the
    // NaN from (-inf) - (-inf) on fully-padded lanes to 0 -> exp=1, s=0 stays 0.
    return __expf(fminf(dm, 0.0f));
}

// Last-block election counter. Zero-initialized at module load; the elected
// last block resets it to 0 at the end of every launch, so repeated graph
// replays see a clean counter without any host-side involvement.
__device__ int fedtgp_done_ctr = 0;

__global__ __launch_bounds__(256) void fedtgp_fused(
    const float* __restrict__ logits,
    const int*   __restrict__ labels,
    const float* __restrict__ features,
    const float* __restrict__ protos,
    double* __restrict__ ce_part,
    double* __restrict__ pl_part,
    float* __restrict__ out,
    int B, int C, int D, int nb, double invB)
{
    const int tid  = threadIdx.x;
    const int lane = tid & 63;
    const int wv   = tid >> 6;
    const int row  = blockIdx.x * 4 + wv;

    __shared__ double sc[4], sp[4];
    __shared__ int amLastSh;

    float ce_b = 0.f, pl_b = 0.f;
    const bool valid = (row < B);

    if (valid) {
        const int   lab  = labels[row];
        const float* lrow = logits + (size_t)row * C;
        const int C4 = C >> 2;
        const int D4 = D >> 2;
        const float4* l4 = (const float4*)lrow;
        const float4* f4 = (const float4*)(features + (size_t)row * D);
        const float4* p4 = (const float4*)(protos   + (size_t)lab * D);

        float m = -INFINITY;
        float s = 0.f;
        float q = 0.f;

        // ---- chunked register pass over logits (1 chunk for C<=1024) ----
        for (int base = 0; base < C4; base += 256) {
            float4 v[4];
            #pragma unroll
            for (int k = 0; k < 4; ++k) {
                const int idx = base + lane + 64 * k;
                v[k] = (idx < C4) ? l4[idx]
                                  : make_float4(-INFINITY, -INFINITY, -INFINITY, -INFINITY);
            }
            float cm = m;
            #pragma unroll
            for (int k = 0; k < 4; ++k)
                cm = fmaxf(cm, fmaxf(fmaxf(v[k].x, v[k].y), fmaxf(v[k].z, v[k].w)));
            s *= safe_exp(m - cm);
            #pragma unroll
            for (int k = 0; k < 4; ++k) {
                s += safe_exp(v[k].x - cm) + safe_exp(v[k].y - cm)
                   + safe_exp(v[k].z - cm) + safe_exp(v[k].w - cm);
            }
            m = cm;
        }
        // scalar tail (C % 4 != 0; unused for C=1000)
        for (int c = (C4 << 2) + lane; c < C; c += 64) {
            const float x  = lrow[c];
            const float cm = fmaxf(m, x);
            s = s * safe_exp(m - cm) + safe_exp(x - cm);
            m = cm;
        }

        const float ll = lrow[lab];   // broadcast load, issued before MSE work

        // ---- prototype MSE: 2 float4 per lane (D=512), padded-zero safe ----
        #pragma unroll
        for (int k = 0; k < 2; ++k) {
            const int idx = lane + 64 * k;
            float4 f = make_float4(0.f, 0.f, 0.f, 0.f);
            float4 p = make_float4(0.f, 0.f, 0.f, 0.f);
            if (idx < D4) { f = f4[idx]; p = p4[idx]; }
            const float dx = f.x - p.x, dy = f.y - p.y;
            const float dz = f.z - p.z, dw = f.w - p.w;
            q += dx * dx + dy * dy + dz * dz + dw * dw;
        }
        for (int idx = lane + 128; idx < D4; idx += 64) {  // D>1024 fallback
            const float4 f = f4[idx];
            const float4 p = p4[idx];
            const float dx = f.x - p.x, dy = f.y - p.y;
            const float dz = f.z - p.z, dw = f.w - p.w;
            q += dx * dx + dy * dy + dz * dz + dw * dw;
        }
        for (int d = (D4 << 2) + lane; d < D; d += 64) {   // D%4 tail
            const float df = features[(size_t)row * D + d]
                           - protos[(size_t)lab * D + d];
            q += df * df;
        }

        // ---- wave reduction: max butterfly -> single rescale -> sum butterfly
        float M = m;
        #pragma unroll
        for (int off = 32; off > 0; off >>= 1)
            M = fmaxf(M, __shfl_xor(M, off, 64));
        s *= safe_exp(m - M);       // one exp instead of 12 on the old path
        #pragma unroll
        for (int off = 32; off > 0; off >>= 1) {
            s += __shfl_xor(s, off, 64);
            q += __shfl_xor(q, off, 64);
        }

        ce_b = (M + __logf(s)) - ll;
        pl_b = q / (float)D;
    }

    if (lane == 0) {
        sc[wv] = valid ? (double)ce_b : 0.0;
        sp[wv] = valid ? (double)pl_b : 0.0;
    }
    __syncthreads();
    if (tid == 0) {
        ce_part[blockIdx.x] = sc[0] + sc[1] + sc[2] + sc[3];
        pl_part[blockIdx.x] = sp[0] + sp[1] + sp[2] + sp[3];
        __threadfence();   // release: partials visible before the ticket bump
        amLastSh = (atomicAdd(&fedtgp_done_ctr, 1) == nb - 1) ? 1 : 0;
    }
    __syncthreads();

    // ---- fused finalize: exactly one block survives to here ----
    if (amLastSh) {
        __threadfence();   // acquire: see every other block's partials
        double c = 0.0, p = 0.0;
        for (int i = tid; i < nb; i += 256) {
            c += ce_part[i];
            p += pl_part[i];
        }
        #pragma unroll
        for (int off = 32; off > 0; off >>= 1) {
            c += __shfl_xor(c, off, 64);
            p += __shfl_xor(p, off, 64);
        }
        __shared__ double rc[4], rp[4];
        if (lane == 0) { rc[wv] = c; rp[wv] = p; }
        __syncthreads();
        if (tid == 0) {
            const double cs = rc[0] + rc[1] + rc[2] + rc[3];
            const double ps = rp[0] + rp[1] + rp[2] + rp[3];
            float ce = (float)(cs * invB);
            float pl = (float)(ps * invB);
            if (!isfinite(ce)) ce = 0.0f;          // ce_loss = where(isfinite, ce, 0)
            float tot = ce + pl;                   // LAMDA = 1.0
            if (!isfinite(tot)) tot = ce;          // total = where(isfinite, total, ce)
            out[0] = tot;
            out[1] = ce;
            out[2] = pl;
            atomicExch(&fedtgp_done_ctr, 0);       // reset for the next replay
        }
    }
}

extern "C" void kernel_launch(void* const* d_in, const int* in_sizes, int n_in,
                              void* d_out, int out_size, void* d_ws, size_t ws_size,
                              hipStream_t stream)
{
    const float* logits   = (const float*)d_in[0];
    const int*   labels   = (const int*)  d_in[1];
    const float* features = (const float*)d_in[2];
    const float* protos   = (const float*)d_in[3];
    float* out = (float*)d_out;

    const int B = in_sizes[1];              // 16384
    const int C = in_sizes[0] / B;          // 1000
    const int D = in_sizes[2] / B;          // 512

    int nb = (B + 3) / 4;                   // one row per wave, 4 waves/block
    const size_t need_per_block = 2 * sizeof(double);
    if ((size_t)nb * need_per_block > ws_size) {
        nb = (int)(ws_size / need_per_block); // degenerate-guard; never hit here
        if (nb < 1) nb = 1;
    }

    double* ce_part = (double*)d_ws;
    double* pl_part = ce_part + nb;

    fedtgp_fused<<<nb, 256, 0, stream>>>(logits, labels, features, protos,
                                         ce_part, pl_part, out, B, C, D, nb,
                                         1.0 / (double)B);
}

// Round 3
// 122.109 us; speedup vs baseline: 2.3523x; 2.3523x over previous
//
#include <hip/hip_runtime.h>
#include <math.h>

// FedTGPClientLoss: fused CE (log-softmax gather) + prototype-MSE.
// B=16384, C=1000, D=512.
// R6 = R5 resubmit (R5 bench failed at container level, no kernel signal).
// Two kernels (R4's single-ticket last-block fusion serialized at
// ~50ns/atomic x 4096 blocks = 200us -- reverted). Rows kernel: one row per
// wave, ZERO barriers, zero LDS. All 8 vector loads per lane issued
// unconditionally with CLAMPED addresses (no divergent ternary-load blocks --
// R3/R4 compiled those to serialized load-wait chains, VGPR_Count=20).
// Out-of-range elements neutralized by selects after the loads. Per-row
// float2 partial written by lane 0; 1-block finalize accumulates in double.

#ifndef INFINITY
#define INFINITY __builtin_inff()
#endif

__device__ __forceinline__ float safe_exp(float dm) {
    // exp(min(dm,0)): dm <= 0 mathematically; fmin also flushes the NaN from
    // (-inf) - (-inf) on fully-padded lanes to 0 -> exp=1 paired with s=0.
    return __expf(fminf(dm, 0.0f));
}

__global__ __launch_bounds__(256) void fedtgp_rows(
    const float* __restrict__ logits,
    const int*   __restrict__ labels,
    const float* __restrict__ features,
    const float* __restrict__ protos,
    float2* __restrict__ part,          // per-row (ce, pl)
    int B, int C, int D)
{
    const int tid  = threadIdx.x;
    const int lane = tid & 63;
    const int wv   = tid >> 6;
    const int row  = blockIdx.x * 4 + wv;
    if (row >= B) return;

    const int lab = labels[row];        // issued first: feeds proto base addr
    const int C4 = C >> 2;
    const int D4 = D >> 2;
    const float* lrow = logits + (size_t)row * C;

    float ce, pl;

    if (C4 >= 64 && C4 <= 256 && D4 >= 64 && D4 <= 128 &&
        (C & 3) == 0 && (D & 3) == 0) {
        // ---- fast path for the benchmarked shape (C=1000 -> C4=250,
        //      D=512 -> D4=128). All loads unconditional, clamped. ----
        const float4* l4 = (const float4*)lrow;
        const float4* f4 = (const float4*)(features + (size_t)row * D);
        const float4* p4 = (const float4*)(protos   + (size_t)lab * D);

        const int i1 = min(lane + 64,  C4 - 1);
        const int i2 = min(lane + 128, C4 - 1);
        const int i3 = min(lane + 192, C4 - 1);
        const int j1 = min(lane + 64,  D4 - 1);

        // 8 vector loads + 1 broadcast load, all independent, all in flight.
        float4 v0 = l4[lane];
        float4 v1 = l4[i1];
        float4 v2 = l4[i2];
        float4 v3 = l4[i3];
        float4 f0 = f4[lane];
        float4 f1 = f4[j1];
        float4 p0 = p4[lane];
        float4 p1 = p4[j1];
        const float ll = lrow[lab];

        const bool b1 = (lane + 64  < C4);
        const bool b2 = (lane + 128 < C4);
        const bool b3 = (lane + 192 < C4);
        const bool d1 = (lane + 64  < D4);
        const float NI = -INFINITY;
        v1.x = b1 ? v1.x : NI; v1.y = b1 ? v1.y : NI;
        v1.z = b1 ? v1.z : NI; v1.w = b1 ? v1.w : NI;
        v2.x = b2 ? v2.x : NI; v2.y = b2 ? v2.y : NI;
        v2.z = b2 ? v2.z : NI; v2.w = b2 ? v2.w : NI;
        v3.x = b3 ? v3.x : NI; v3.y = b3 ? v3.y : NI;
        v3.z = b3 ? v3.z : NI; v3.w = b3 ? v3.w : NI;

        // per-lane max over 16 values
        float m = fmaxf(fmaxf(fmaxf(v0.x, v0.y), fmaxf(v0.z, v0.w)),
                        fmaxf(fmaxf(v1.x, v1.y), fmaxf(v1.z, v1.w)));
        m = fmaxf(m, fmaxf(fmaxf(v2.x, v2.y), fmaxf(v2.z, v2.w)));
        m = fmaxf(m, fmaxf(fmaxf(v3.x, v3.y), fmaxf(v3.z, v3.w)));

        float s = safe_exp(v0.x - m) + safe_exp(v0.y - m)
                + safe_exp(v0.z - m) + safe_exp(v0.w - m);
        s += safe_exp(v1.x - m) + safe_exp(v1.y - m)
           + safe_exp(v1.z - m) + safe_exp(v1.w - m);
        s += safe_exp(v2.x - m) + safe_exp(v2.y - m)
           + safe_exp(v2.z - m) + safe_exp(v2.w - m);
        s += safe_exp(v3.x - m) + safe_exp(v3.y - m)
           + safe_exp(v3.z - m) + safe_exp(v3.w - m);

        // prototype MSE
        float dx = f0.x - p0.x, dy = f0.y - p0.y;
        float dz = f0.z - p0.z, dw = f0.w - p0.w;
        float q = dx * dx + dy * dy + dz * dz + dw * dw;
        dx = f1.x - p1.x; dy = f1.y - p1.y;
        dz = f1.z - p1.z; dw = f1.w - p1.w;
        float q1 = dx * dx + dy * dy + dz * dz + dw * dw;
        q += d1 ? q1 : 0.0f;

        // wave reduction: max butterfly -> one rescale exp -> sum butterfly
        float M = m;
        #pragma unroll
        for (int off = 32; off > 0; off >>= 1)
            M = fmaxf(M, __shfl_xor(M, off, 64));
        s *= safe_exp(m - M);
        #pragma unroll
        for (int off = 32; off > 0; off >>= 1) {
            s += __shfl_xor(s, off, 64);
            q += __shfl_xor(q, off, 64);
        }

        ce = (M + __logf(s)) - ll;
        pl = q / (float)D;
    } else {
        // ---- generic fallback (correctness only; not hit for bench shape) --
        float m = -INFINITY, s = 0.f, q = 0.f;
        for (int c = lane; c < C; c += 64) {
            const float x  = lrow[c];
            const float cm = fmaxf(m, x);
            s = s * safe_exp(m - cm) + safe_exp(x - cm);
            m = cm;
        }
        for (int d = lane; d < D; d += 64) {
            const float df = features[(size_t)row * D + d]
                           - protos[(size_t)lab * D + d];
            q += df * df;
        }
        const float ll = lrow[lab];
        #pragma unroll
        for (int off = 32; off > 0; off >>= 1) {
            const float om = __shfl_xor(m, off, 64);
            const float os = __shfl_xor(s, off, 64);
            q += __shfl_xor(q, off, 64);
            const float nm = fmaxf(m, om);
            s = s * safe_exp(m - nm) + os * safe_exp(om - nm);
            m = nm;
        }
        ce = (m + __logf(s)) - ll;
        pl = q / (float)D;
    }

    if (lane == 0) part[row] = make_float2(ce, pl);
}

__global__ __launch_bounds__(1024) void fedtgp_finalize(
    const float2* __restrict__ part,
    float* __restrict__ out,
    int B, double invB)
{
    const int tid  = threadIdx.x;
    const int lane = tid & 63;
    const int wv   = tid >> 6;
    __shared__ double rc[16];
    __shared__ double rp[16];

    double c = 0.0, p = 0.0;
    for (int i = tid; i < B; i += 1024) {
        const float2 v = part[i];
        c += (double)v.x;
        p += (double)v.y;
    }
    #pragma unroll
    for (int off = 32; off > 0; off >>= 1) {
        c += __shfl_xor(c, off, 64);
        p += __shfl_xor(p, off, 64);
    }
    if (lane == 0) { rc[wv] = c; rp[wv] = p; }
    __syncthreads();

    if (tid == 0) {
        double cs = 0.0, ps = 0.0;
        #pragma unroll
        for (int k = 0; k < 16; ++k) { cs += rc[k]; ps += rp[k]; }
        float ce = (float)(cs * invB);
        float pl = (float)(ps * invB);
        if (!isfinite(ce)) ce = 0.0f;          // ce_loss = where(isfinite, ce, 0)
        float tot = ce + pl;                   // LAMDA = 1.0
        if (!isfinite(tot)) tot = ce;          // total = where(isfinite, total, ce)
        out[0] = tot;
        out[1] = ce;
        out[2] = pl;
    }
}

extern "C" void kernel_launch(void* const* d_in, const int* in_sizes, int n_in,
                              void* d_out, int out_size, void* d_ws, size_t ws_size,
                              hipStream_t stream)
{
    const float* logits   = (const float*)d_in[0];
    const int*   labels   = (const int*)  d_in[1];
    const float* features = (const float*)d_in[2];
    const float* protos   = (const float*)d_in[3];
    float* out = (float*)d_out;

    const int B = in_sizes[1];              // 16384
    const int C = in_sizes[0] / B;          // 1000
    const int D = in_sizes[2] / B;          // 512

    float2* part = (float2*)d_ws;           // B * 8 bytes = 128 KB << ws_size

    const int nb = (B + 3) / 4;             // one row per wave, 4 waves/block
    fedtgp_rows<<<nb, 256, 0, stream>>>(logits, labels, features, protos,
                                        part, B, C, D);
    fedtgp_finalize<<<1, 1024, 0, stream>>>(part, out, B, 1.0 / (double)B);
}